// Round 1
// baseline (329.756 us; speedup 1.0000x reference)
//
#include <hip/hip_runtime.h>
#include <math.h>

#define HW 262144          // 512*512
#define NB 4
#define NC 4
#define ND 32
#define NPIX (NB * HW)     // 1048576
#define EPSF 1e-8f

// ws header (floats):
#define OFF_SUMS    0      // 2*4*4*32 = 1024
#define OFF_COUNTS  1024   // 2*4*4 = 32
#define OFF_CENTERS 1056   // 1024
#define OFF_CNORM   2080   // 32
#define OFF_PART    2112   // 64 shadow copies x 4 partials = 256
#define HDR_BYTES   9472   // 2368 floats

__device__ __forceinline__ float wave_sum64(float v) {
#pragma unroll
  for (int off = 32; off > 0; off >>= 1) v += __shfl_xor(v, off, 64);
  return v;
}

// -------- Pass A: per-pixel stats from logits --------
__global__ __launch_bounds__(256) void passA(
    const float* __restrict__ pm, const float* __restrict__ pa,
    unsigned char* __restrict__ rec, float* __restrict__ cfm,
    float* __restrict__ cfa, float* __restrict__ cem, float* __restrict__ cea) {
  int stride = gridDim.x * blockDim.x;
  for (int p = blockIdx.x * blockDim.x + threadIdx.x; p < NPIX; p += stride) {
    int b = p >> 18;
    int px = p & (HW - 1);
    const float* x = pm + ((size_t)(b * NC) << 18) + px;
    float x0 = x[0], x1 = x[HW], x2 = x[2 * HW], x3 = x[3 * HW];
    const float* y = pa + ((size_t)(b * NC) << 18) + px;
    float y0 = y[0], y1 = y[HW], y2 = y[2 * HW], y3 = y[3 * HW];
    int hm = 0; float bm = x0;
    if (x1 > bm) { bm = x1; hm = 1; }
    if (x2 > bm) { bm = x2; hm = 2; }
    if (x3 > bm) { bm = x3; hm = 3; }
    int ha = 0; float ba = y0;
    if (y1 > ba) { ba = y1; ha = 1; }
    if (y2 > ba) { ba = y2; ha = 2; }
    if (y3 > ba) { ba = y3; ha = 3; }
    float sem = expf(x0 - bm) + expf(x1 - bm) + expf(x2 - bm) + expf(x3 - bm);
    float sea = expf(y0 - ba) + expf(y1 - ba) + expf(y2 - ba) + expf(y3 - ba);
    float confm = 1.0f / sem, confa = 1.0f / sea;
    int mk = (confm >= confa) ? 1 : 0;
    int lab = mk ? hm : ha;
    float xl = lab == 0 ? x0 : lab == 1 ? x1 : lab == 2 ? x2 : x3;
    float yl = lab == 0 ? y0 : lab == 1 ? y1 : lab == 2 ? y2 : y3;
    cem[p] = bm - xl + logf(sem);   // CE of pred_main at pseudo_label
    cea[p] = ba - yl + logf(sea);   // CE of pred_aux  at pseudo_label
    cfm[p] = confm;
    cfa[p] = confa;
    rec[p] = (unsigned char)(hm | (ha << 2) | (mk << 4));
  }
}

// -------- Pass B: confidence-weighted class-center sums (register-accumulated) --------
#define ITER_B 16   // pixels per lane per block; chunk = 64*ITER_B = 1024 px
__global__ __launch_bounds__(256) void passB(
    const float* __restrict__ fm, const float* __restrict__ fa,
    const unsigned char* __restrict__ rec, const float* __restrict__ cfm,
    const float* __restrict__ cfa, float* __restrict__ sums,
    float* __restrict__ counts) {
  int b = blockIdx.y;
  int wave = threadIdx.x >> 6;
  int lane = threadIdx.x & 63;
  int px0 = blockIdx.x * (64 * ITER_B) + lane;

  float acc[8][8];   // [dd][0..3]=main cls, [4..7]=aux cls
#pragma unroll
  for (int i = 0; i < 8; ++i)
#pragma unroll
    for (int j = 0; j < 8; ++j) acc[i][j] = 0.f;
  float cnt[8];
#pragma unroll
  for (int j = 0; j < 8; ++j) cnt[j] = 0.f;

  const float* fmp[8];
  const float* fap[8];
#pragma unroll
  for (int dd = 0; dd < 8; ++dd) {
    int d = wave + dd * 4;
    size_t off = ((size_t)(b * ND + d)) << 18;
    fmp[dd] = fm + off;
    fap[dd] = fa + off;
  }
  int pbase = b << 18;

  for (int it = 0; it < ITER_B; ++it) {
    int px = px0 + it * 64;
    int p = pbase + px;
    unsigned r = rec[p];
    float cm = cfm[p], ca = cfa[p];
    int hm = r & 3, ha = (r >> 2) & 3, mk = (r >> 4) & 1;
    float w0 = hm == 0 ? cm : 0.f, w1 = hm == 1 ? cm : 0.f;
    float w2 = hm == 2 ? cm : 0.f, w3 = hm == 3 ? cm : 0.f;
    float u0 = ha == 0 ? ca : 0.f, u1 = ha == 1 ? ca : 0.f;
    float u2 = ha == 2 ? ca : 0.f, u3 = ha == 3 ? ca : 0.f;
    if (wave == 0) {
      cnt[0] += hm == 0 ? 1.f : 0.f; cnt[1] += hm == 1 ? 1.f : 0.f;
      cnt[2] += hm == 2 ? 1.f : 0.f; cnt[3] += hm == 3 ? 1.f : 0.f;
      cnt[4] += ha == 0 ? 1.f : 0.f; cnt[5] += ha == 1 ? 1.f : 0.f;
      cnt[6] += ha == 2 ? 1.f : 0.f; cnt[7] += ha == 3 ? 1.f : 0.f;
    }
#pragma unroll
    for (int dd = 0; dd < 8; ++dd) {
      float vm = fmp[dd][px];
      float va = fap[dd][px];
      float ps = mk ? vm : va;
      acc[dd][0] = fmaf(w0, ps, acc[dd][0]);
      acc[dd][1] = fmaf(w1, ps, acc[dd][1]);
      acc[dd][2] = fmaf(w2, ps, acc[dd][2]);
      acc[dd][3] = fmaf(w3, ps, acc[dd][3]);
      acc[dd][4] = fmaf(u0, ps, acc[dd][4]);
      acc[dd][5] = fmaf(u1, ps, acc[dd][5]);
      acc[dd][6] = fmaf(u2, ps, acc[dd][6]);
      acc[dd][7] = fmaf(u3, ps, acc[dd][7]);
    }
  }

#pragma unroll
  for (int dd = 0; dd < 8; ++dd) {
#pragma unroll
    for (int j = 0; j < 8; ++j) {
      float v = wave_sum64(acc[dd][j]);
      if (lane == 0) {
        int map = j >> 2, cls = j & 3, d = wave + dd * 4;
        atomicAdd(&sums[((map * NB + b) * NC + cls) * ND + d], v);
      }
    }
  }
  if (wave == 0) {
#pragma unroll
    for (int j = 0; j < 8; ++j) {
      float v = wave_sum64(cnt[j]);
      if (lane == 0) atomicAdd(&counts[(j >> 2) * 16 + b * 4 + (j & 3)], v);
    }
  }
}

// -------- Pass C: finalize centers + norms (1 block) --------
__global__ __launch_bounds__(1024) void passC(
    const float* __restrict__ sums, const float* __restrict__ counts,
    float* __restrict__ centers, float* __restrict__ cnorm) {
  int t = threadIdx.x;          // 0..1023 -> [map][b][cls][d]
  int g = t >> 5;               // (map,b,cls)
  float cv = sums[t] / fmaxf(counts[g], 1.f);
  centers[t] = cv;
  float s = cv * cv;
#pragma unroll
  for (int off = 16; off > 0; off >>= 1) s += __shfl_xor(s, off, 32);
  if ((t & 31) == 0) cnorm[g] = fmaxf(sqrtf(s), EPSF);
}

// -------- Pass D: per-pixel cosine similarity + weighted reductions --------
__global__ __launch_bounds__(256) void passD(
    const float* __restrict__ fm, const float* __restrict__ fa,
    const unsigned char* __restrict__ rec, const float* __restrict__ cem,
    const float* __restrict__ cea, const float* __restrict__ centers,
    const float* __restrict__ cnorm, float* __restrict__ part) {
  __shared__ float sc[1024];    // [d][map][b][cls] -> conflict-free (lanes differ in cls)
  __shared__ float scn[32];
  __shared__ float red[4][4];
  for (int i = threadIdx.x; i < 1024; i += blockDim.x) {
    int d = i & 31, cls = (i >> 5) & 3, bb = (i >> 7) & 3, mp = i >> 9;
    sc[d * 32 + mp * 16 + bb * 4 + cls] = centers[i];
  }
  if (threadIdx.x < 32) scn[threadIdx.x] = cnorm[threadIdx.x];
  __syncthreads();

  float s0 = 0.f, s1 = 0.f, s2 = 0.f, s3 = 0.f;
  int stride = gridDim.x * blockDim.x;
  for (int p = blockIdx.x * blockDim.x + threadIdx.x; p < NPIX; p += stride) {
    int b = p >> 18;
    int px = p & (HW - 1);
    unsigned r = rec[p];
    int hm = r & 3, ha = (r >> 2) & 3, mk = (r >> 4) & 1;
    const float* fmb = fm + (((size_t)(b * ND)) << 18) + px;
    const float* fab = fa + (((size_t)(b * ND)) << 18) + px;
    int im = b * 4 + hm;        // map 0 index
    int ia = 16 + b * 4 + ha;   // map 1 index
    float nm = 0.f, na = 0.f, fn2 = 0.f;
#pragma unroll
    for (int d = 0; d < ND; ++d) {
      float vm = fmb[(size_t)d << 18];
      float va = fab[(size_t)d << 18];
      float ps = mk ? vm : va;
      nm = fmaf(ps, sc[d * 32 + im], nm);
      na = fmaf(ps, sc[d * 32 + ia], na);
      fn2 = fmaf(ps, ps, fn2);
    }
    float fn = fmaxf(sqrtf(fn2), EPSF);
    float rm = nm / (fn * scn[im]);
    float ra = na / (fn * scn[ia]);
    s0 += cem[p] * ra;   // sum(ce_main * rel_aux)
    s1 += ra;            // sum(rel_aux)
    s2 += cea[p] * rm;   // sum(ce_aux * rel_main)
    s3 += rm;            // sum(rel_main)
  }
  s0 = wave_sum64(s0); s1 = wave_sum64(s1);
  s2 = wave_sum64(s2); s3 = wave_sum64(s3);
  int wave = threadIdx.x >> 6, lane = threadIdx.x & 63;
  if (lane == 0) { red[wave][0] = s0; red[wave][1] = s1; red[wave][2] = s2; red[wave][3] = s3; }
  __syncthreads();
  if (threadIdx.x < 4) {
    float v = red[0][threadIdx.x] + red[1][threadIdx.x] +
              red[2][threadIdx.x] + red[3][threadIdx.x];
    atomicAdd(&part[(blockIdx.x & 63) * 4 + threadIdx.x], v);
  }
}

// -------- Pass E: final scalar --------
__global__ __launch_bounds__(64) void passE(const float* __restrict__ part,
                                            float* __restrict__ out) {
  int t = threadIdx.x;  // 64 lanes, one shadow copy each
  float a0 = part[t * 4 + 0], a1 = part[t * 4 + 1];
  float a2 = part[t * 4 + 2], a3 = part[t * 4 + 3];
  a0 = wave_sum64(a0); a1 = wave_sum64(a1);
  a2 = wave_sum64(a2); a3 = wave_sum64(a3);
  if (t == 0) out[0] = a0 / a1 + a2 / a3;
}

extern "C" void kernel_launch(void* const* d_in, const int* in_sizes, int n_in,
                              void* d_out, int out_size, void* d_ws, size_t ws_size,
                              hipStream_t stream) {
  const float* pm = (const float*)d_in[0];
  const float* pa = (const float*)d_in[1];
  const float* fm = (const float*)d_in[2];
  const float* fa = (const float*)d_in[3];

  float* wsf = (float*)d_ws;
  float* sums = wsf + OFF_SUMS;
  float* counts = wsf + OFF_COUNTS;
  float* centers = wsf + OFF_CENTERS;
  float* cnorm = wsf + OFF_CNORM;
  float* part = wsf + OFF_PART;
  unsigned char* rec = (unsigned char*)d_ws + HDR_BYTES;
  float* cfm = (float*)((char*)d_ws + HDR_BYTES + NPIX);
  float* cfa = cfm + NPIX;
  float* cem = cfa + NPIX;
  float* cea = cem + NPIX;

  hipMemsetAsync(d_ws, 0, HDR_BYTES, stream);
  passA<<<1024, 256, 0, stream>>>(pm, pa, rec, cfm, cfa, cem, cea);
  passB<<<dim3(256, 4), 256, 0, stream>>>(fm, fa, rec, cfm, cfa, sums, counts);
  passC<<<1, 1024, 0, stream>>>(sums, counts, centers, cnorm);
  passD<<<1024, 256, 0, stream>>>(fm, fa, rec, cem, cea, centers, cnorm, part);
  passE<<<1, 64, 0, stream>>>(part, (float*)d_out);
}

// Round 2
// 206.096 us; speedup vs baseline: 1.6000x; 1.6000x over previous
//
#include <hip/hip_runtime.h>
#include <math.h>

#define HW 262144          // 512*512
#define NB 4
#define NC 4
#define ND 32
#define NPIX (NB * HW)     // 1048576
#define EPSF 1e-8f

// ws header (floats):
#define OFF_SUMS    0      // 2*4*4*32 = 1024
#define OFF_COUNTS  1024   // 2*4*4 = 32
#define OFF_CENTERS 1056   // 1024
#define OFF_CNORM   2080   // 32
#define OFF_PART    2112   // 64 shadow copies x 4 partials = 256
#define HDR_BYTES   9472   // 2368 floats

// compile-time float4 element select (pure cndmask chain, folds at const e —
// avoids address-taken arrays that can demote to scratch)
#define ELEM(v,e) ((e)==0?(v).x:(e)==1?(v).y:(e)==2?(v).z:(v).w)

__device__ __forceinline__ float wave_sum64(float v) {
#pragma unroll
  for (int off = 32; off > 0; off >>= 1) v += __shfl_xor(v, off, 64);
  return v;
}

// -------- Pass A: per-pixel stats from logits (float4: 4 px/lane) --------
__global__ __launch_bounds__(256) void passA(
    const float* __restrict__ pm, const float* __restrict__ pa,
    unsigned* __restrict__ recu, float4* __restrict__ cfm4,
    float4* __restrict__ cfa4, float4* __restrict__ cem4,
    float4* __restrict__ cea4) {
  int p4 = blockIdx.x * 256 + threadIdx.x;   // 0..262143 float4 groups
  int b = p4 >> 16;
  int px4 = p4 & 0xFFFF;
  const float4* xb = (const float4*)pm + (((long)b * NC) << 16) + px4;
  const float4* yb = (const float4*)pa + (((long)b * NC) << 16) + px4;
  float4 X0 = xb[0], X1 = xb[1 << 16], X2 = xb[2 << 16], X3 = xb[3 << 16];
  float4 Y0 = yb[0], Y1 = yb[1 << 16], Y2 = yb[2 << 16], Y3 = yb[3 << 16];
  float4 cem, cea, cfm, cfa;
  unsigned ru = 0;
#pragma unroll
  for (int e = 0; e < 4; ++e) {
    float x0 = ELEM(X0, e), x1 = ELEM(X1, e), x2 = ELEM(X2, e), x3 = ELEM(X3, e);
    float y0 = ELEM(Y0, e), y1 = ELEM(Y1, e), y2 = ELEM(Y2, e), y3 = ELEM(Y3, e);
    int hm = 0; float bm = x0;
    if (x1 > bm) { bm = x1; hm = 1; }
    if (x2 > bm) { bm = x2; hm = 2; }
    if (x3 > bm) { bm = x3; hm = 3; }
    int ha = 0; float ba = y0;
    if (y1 > ba) { ba = y1; ha = 1; }
    if (y2 > ba) { ba = y2; ha = 2; }
    if (y3 > ba) { ba = y3; ha = 3; }
    float sem = expf(x0 - bm) + expf(x1 - bm) + expf(x2 - bm) + expf(x3 - bm);
    float sea = expf(y0 - ba) + expf(y1 - ba) + expf(y2 - ba) + expf(y3 - ba);
    float confm = 1.0f / sem, confa = 1.0f / sea;
    int mk = (confm >= confa) ? 1 : 0;
    int lab = mk ? hm : ha;
    float xl = lab == 0 ? x0 : lab == 1 ? x1 : lab == 2 ? x2 : x3;
    float yl = lab == 0 ? y0 : lab == 1 ? y1 : lab == 2 ? y2 : y3;
    float vem = bm - xl + logf(sem);
    float vea = ba - yl + logf(sea);
    if (e == 0) { cem.x = vem; cea.x = vea; cfm.x = confm; cfa.x = confa; }
    if (e == 1) { cem.y = vem; cea.y = vea; cfm.y = confm; cfa.y = confa; }
    if (e == 2) { cem.z = vem; cea.z = vea; cfm.z = confm; cfa.z = confa; }
    if (e == 3) { cem.w = vem; cea.w = vea; cfm.w = confm; cfa.w = confa; }
    ru |= (unsigned)(hm | (ha << 2) | (mk << 4)) << (8 * e);
  }
  cem4[p4] = cem; cea4[p4] = cea; cfm4[p4] = cfm; cfa4[p4] = cfa;
  recu[p4] = ru;
}

// -------- Pass B: class-center sums, 2 channels/lane, float4 pixels --------
// grid: (128 pixel-chunks, 16 = b*4 + channel-group), block 256 (4 waves)
// chunk = 512 float4 = 2048 px; 8 iters of 64 float4 per wave-lane
__global__ __launch_bounds__(256) void passB(
    const float* __restrict__ fm, const float* __restrict__ fa,
    const unsigned* __restrict__ recu, const float4* __restrict__ cfm4,
    const float4* __restrict__ cfa4, float* __restrict__ sums,
    float* __restrict__ counts) {
  int b = blockIdx.y >> 2;
  int cg = blockIdx.y & 3;
  int wave = threadIdx.x >> 6;
  int lane = threadIdx.x & 63;
  int ch0 = cg * 8 + wave * 2;            // this wave's 2 channels
  bool do_cnt = (cg == 0 && wave == 0);

  const float4* f0m = (const float4*)fm + (((long)(b * ND + ch0)) << 16);
  const float4* f0a = (const float4*)fa + (((long)(b * ND + ch0)) << 16);
  const float4* f1m = f0m + (1L << 16);
  const float4* f1a = f0a + (1L << 16);
  int mbase = b << 16;                    // metadata float4 base
  int base4 = blockIdx.x * 512 + lane;    // float4 index of lane's first group

  float acc[2][8];
#pragma unroll
  for (int c = 0; c < 2; ++c)
#pragma unroll
    for (int j = 0; j < 8; ++j) acc[c][j] = 0.f;
  float cnt[8];
#pragma unroll
  for (int j = 0; j < 8; ++j) cnt[j] = 0.f;

#pragma unroll 2
  for (int it = 0; it < 8; ++it) {
    int idx4 = base4 + it * 64;
    unsigned ru = recu[mbase + idx4];
    float4 cm4 = cfm4[mbase + idx4];
    float4 ca4 = cfa4[mbase + idx4];
    float4 v0m = f0m[idx4], v0a = f0a[idx4];
    float4 v1m = f1m[idx4], v1a = f1a[idx4];
#pragma unroll
    for (int e = 0; e < 4; ++e) {
      unsigned r = (ru >> (8 * e)) & 0xffu;
      int hm = r & 3, ha = (r >> 2) & 3, mk = (r >> 4) & 1;
      float cm = ELEM(cm4, e), ca = ELEM(ca4, e);
      float w0 = hm == 0 ? cm : 0.f, w1 = hm == 1 ? cm : 0.f;
      float w2 = hm == 2 ? cm : 0.f, w3 = hm == 3 ? cm : 0.f;
      float u0 = ha == 0 ? ca : 0.f, u1 = ha == 1 ? ca : 0.f;
      float u2 = ha == 2 ? ca : 0.f, u3 = ha == 3 ? ca : 0.f;
      float p0 = mk ? ELEM(v0m, e) : ELEM(v0a, e);
      float p1 = mk ? ELEM(v1m, e) : ELEM(v1a, e);
      acc[0][0] = fmaf(w0, p0, acc[0][0]); acc[0][1] = fmaf(w1, p0, acc[0][1]);
      acc[0][2] = fmaf(w2, p0, acc[0][2]); acc[0][3] = fmaf(w3, p0, acc[0][3]);
      acc[0][4] = fmaf(u0, p0, acc[0][4]); acc[0][5] = fmaf(u1, p0, acc[0][5]);
      acc[0][6] = fmaf(u2, p0, acc[0][6]); acc[0][7] = fmaf(u3, p0, acc[0][7]);
      acc[1][0] = fmaf(w0, p1, acc[1][0]); acc[1][1] = fmaf(w1, p1, acc[1][1]);
      acc[1][2] = fmaf(w2, p1, acc[1][2]); acc[1][3] = fmaf(w3, p1, acc[1][3]);
      acc[1][4] = fmaf(u0, p1, acc[1][4]); acc[1][5] = fmaf(u1, p1, acc[1][5]);
      acc[1][6] = fmaf(u2, p1, acc[1][6]); acc[1][7] = fmaf(u3, p1, acc[1][7]);
      if (do_cnt) {
        cnt[0] += hm == 0 ? 1.f : 0.f; cnt[1] += hm == 1 ? 1.f : 0.f;
        cnt[2] += hm == 2 ? 1.f : 0.f; cnt[3] += hm == 3 ? 1.f : 0.f;
        cnt[4] += ha == 0 ? 1.f : 0.f; cnt[5] += ha == 1 ? 1.f : 0.f;
        cnt[6] += ha == 2 ? 1.f : 0.f; cnt[7] += ha == 3 ? 1.f : 0.f;
      }
    }
  }

#pragma unroll
  for (int c = 0; c < 2; ++c)
#pragma unroll
    for (int j = 0; j < 8; ++j) {
      float v = wave_sum64(acc[c][j]);
      if (lane == 0) {
        int map = j >> 2, cls = j & 3;
        atomicAdd(&sums[((map * NB + b) * NC + cls) * ND + ch0 + c], v);
      }
    }
  if (do_cnt) {
#pragma unroll
    for (int j = 0; j < 8; ++j) {
      float v = wave_sum64(cnt[j]);
      if (lane == 0) atomicAdd(&counts[(j >> 2) * 16 + b * 4 + (j & 3)], v);
    }
  }
}

// -------- Pass C: finalize centers + norms (1 block) --------
__global__ __launch_bounds__(1024) void passC(
    const float* __restrict__ sums, const float* __restrict__ counts,
    float* __restrict__ centers, float* __restrict__ cnorm) {
  int t = threadIdx.x;          // [map][b][cls][d]
  int g = t >> 5;
  float cv = sums[t] / fmaxf(counts[g], 1.f);
  centers[t] = cv;
  float s = cv * cv;
#pragma unroll
  for (int off = 16; off > 0; off >>= 1) s += __shfl_xor(s, off, 32);
  if ((t & 31) == 0) cnorm[g] = fmaxf(sqrtf(s), EPSF);
}

// -------- Pass D: cosine similarity + weighted reductions (float4) --------
__global__ __launch_bounds__(256) void passD(
    const float* __restrict__ fm, const float* __restrict__ fa,
    const unsigned* __restrict__ recu, const float4* __restrict__ cem4,
    const float4* __restrict__ cea4, const float* __restrict__ centers,
    const float* __restrict__ cnorm, float* __restrict__ part) {
  __shared__ float sc[1024];    // [d][map*16 + b*4 + cls]
  __shared__ float scn[32];
  __shared__ float red[4][4];
  for (int i = threadIdx.x; i < 1024; i += 256) {
    int d = i & 31, cls = (i >> 5) & 3, bb = (i >> 7) & 3, mp = i >> 9;
    sc[d * 32 + mp * 16 + bb * 4 + cls] = centers[i];
  }
  if (threadIdx.x < 32) scn[threadIdx.x] = cnorm[threadIdx.x];
  __syncthreads();

  int p4 = blockIdx.x * 256 + threadIdx.x;   // one float4 group per thread
  int b = p4 >> 16;
  int px4 = p4 & 0xFFFF;
  unsigned ru = recu[p4];
  int im[4], ia[4], mk[4];
#pragma unroll
  for (int e = 0; e < 4; ++e) {
    unsigned r = (ru >> (8 * e)) & 0xffu;
    im[e] = b * 4 + (r & 3);
    ia[e] = 16 + b * 4 + ((r >> 2) & 3);
    mk[e] = (r >> 4) & 1;
  }
  const float4* fmb = (const float4*)fm + (((long)(b * ND)) << 16) + px4;
  const float4* fab = (const float4*)fa + (((long)(b * ND)) << 16) + px4;
  float4 nm = {0.f, 0.f, 0.f, 0.f}, na = {0.f, 0.f, 0.f, 0.f},
         fn2 = {0.f, 0.f, 0.f, 0.f};
#pragma unroll 8
  for (int d = 0; d < ND; ++d) {
    float4 vm = fmb[(long)d << 16];
    float4 va = fab[(long)d << 16];
#pragma unroll
    for (int e = 0; e < 4; ++e) {
      float ps = mk[e] ? ELEM(vm, e) : ELEM(va, e);
      float cim = sc[d * 32 + im[e]];
      float cia = sc[d * 32 + ia[e]];
      if (e == 0) { nm.x = fmaf(ps, cim, nm.x); na.x = fmaf(ps, cia, na.x); fn2.x = fmaf(ps, ps, fn2.x); }
      if (e == 1) { nm.y = fmaf(ps, cim, nm.y); na.y = fmaf(ps, cia, na.y); fn2.y = fmaf(ps, ps, fn2.y); }
      if (e == 2) { nm.z = fmaf(ps, cim, nm.z); na.z = fmaf(ps, cia, na.z); fn2.z = fmaf(ps, ps, fn2.z); }
      if (e == 3) { nm.w = fmaf(ps, cim, nm.w); na.w = fmaf(ps, cia, na.w); fn2.w = fmaf(ps, ps, fn2.w); }
    }
  }
  float4 cem = cem4[p4], cea = cea4[p4];
  float s0 = 0.f, s1 = 0.f, s2 = 0.f, s3 = 0.f;
#pragma unroll
  for (int e = 0; e < 4; ++e) {
    float fn = fmaxf(sqrtf(ELEM(fn2, e)), EPSF);
    float rm = ELEM(nm, e) / (fn * scn[im[e]]);
    float ra = ELEM(na, e) / (fn * scn[ia[e]]);
    s0 = fmaf(ELEM(cem, e), ra, s0);
    s1 += ra;
    s2 = fmaf(ELEM(cea, e), rm, s2);
    s3 += rm;
  }
  s0 = wave_sum64(s0); s1 = wave_sum64(s1);
  s2 = wave_sum64(s2); s3 = wave_sum64(s3);
  int wave = threadIdx.x >> 6, lane = threadIdx.x & 63;
  if (lane == 0) { red[wave][0] = s0; red[wave][1] = s1; red[wave][2] = s2; red[wave][3] = s3; }
  __syncthreads();
  if (threadIdx.x < 4) {
    float v = red[0][threadIdx.x] + red[1][threadIdx.x] +
              red[2][threadIdx.x] + red[3][threadIdx.x];
    atomicAdd(&part[(blockIdx.x & 63) * 4 + threadIdx.x], v);
  }
}

// -------- Pass E: final scalar --------
__global__ __launch_bounds__(64) void passE(const float* __restrict__ part,
                                            float* __restrict__ out) {
  int t = threadIdx.x;
  float a0 = part[t * 4 + 0], a1 = part[t * 4 + 1];
  float a2 = part[t * 4 + 2], a3 = part[t * 4 + 3];
  a0 = wave_sum64(a0); a1 = wave_sum64(a1);
  a2 = wave_sum64(a2); a3 = wave_sum64(a3);
  if (t == 0) out[0] = a0 / a1 + a2 / a3;
}

extern "C" void kernel_launch(void* const* d_in, const int* in_sizes, int n_in,
                              void* d_out, int out_size, void* d_ws, size_t ws_size,
                              hipStream_t stream) {
  const float* pm = (const float*)d_in[0];
  const float* pa = (const float*)d_in[1];
  const float* fm = (const float*)d_in[2];
  const float* fa = (const float*)d_in[3];

  float* wsf = (float*)d_ws;
  float* sums = wsf + OFF_SUMS;
  float* counts = wsf + OFF_COUNTS;
  float* centers = wsf + OFF_CENTERS;
  float* cnorm = wsf + OFF_CNORM;
  float* part = wsf + OFF_PART;
  unsigned char* rec = (unsigned char*)d_ws + HDR_BYTES;
  float* cfm = (float*)((char*)d_ws + HDR_BYTES + NPIX);
  float* cfa = cfm + NPIX;
  float* cem = cfa + NPIX;
  float* cea = cem + NPIX;

  hipMemsetAsync(d_ws, 0, HDR_BYTES, stream);
  passA<<<1024, 256, 0, stream>>>(pm, pa, (unsigned*)rec, (float4*)cfm,
                                  (float4*)cfa, (float4*)cem, (float4*)cea);
  passB<<<dim3(128, 16), 256, 0, stream>>>(fm, fa, (const unsigned*)rec,
                                           (const float4*)cfm,
                                           (const float4*)cfa, sums, counts);
  passC<<<1, 1024, 0, stream>>>(sums, counts, centers, cnorm);
  passD<<<1024, 256, 0, stream>>>(fm, fa, (const unsigned*)rec,
                                  (const float4*)cem, (const float4*)cea,
                                  centers, cnorm, part);
  passE<<<1, 64, 0, stream>>>(part, (float*)d_out);
}